// Round 1
// baseline (8111.829 us; speedup 1.0000x reference)
//
#include <hip/hip_runtime.h>
#include <hip/hip_bf16.h>

#define B_ 2
#define S_ 1024
#define T_ (B_*S_)
#define D_ 2048
#define L_ 4
#define HQ_ 32
#define HKV_ 8
#define HD_ 64
#define I_ 5632
#define EPS_ 1e-5f
#define SCALE_ 0.125f

typedef __attribute__((ext_vector_type(4))) float  float4v;
typedef __attribute__((ext_vector_type(8))) short  short8v;
typedef __attribute__((ext_vector_type(4))) short  short4v;

__device__ __forceinline__ short f2bf(float f) {
  union { float f; unsigned u; } c; c.f = f;
  unsigned u = c.u + 0x7fffu + ((c.u >> 16) & 1u);
  return (short)(u >> 16);
}

// ---------------- transpose f32 [K][N] -> bf16 [N][K] ----------------
__global__ __launch_bounds__(256)
void transpose_bf16(const float* __restrict__ in, short* __restrict__ out,
                    int K, int N) {
  __shared__ float t[32][33];
  const int bx = blockIdx.x * 32;   // N offset
  const int by = blockIdx.y * 32;   // K offset
  const int tx = threadIdx.x, ty = threadIdx.y;
  #pragma unroll
  for (int j = 0; j < 32; j += 8)
    t[ty + j][tx] = in[(size_t)(by + ty + j) * N + bx + tx];
  __syncthreads();
  #pragma unroll
  for (int j = 0; j < 32; j += 8)
    out[(size_t)(bx + ty + j) * K + by + tx] = f2bf(t[tx][ty + j]);
}

// ---------------- embedding gather ----------------
__global__ __launch_bounds__(256)
void embed_gather(const int* __restrict__ ids, const float* __restrict__ embed,
                  float* __restrict__ h) {
  size_t i = (size_t)blockIdx.x * 256 + threadIdx.x;   // over T*D/4
  int t  = (int)(i >> 9);                              // D/4 = 512
  int d4 = (int)(i & 511);
  ((float4v*)h)[i] = ((const float4v*)(embed + (size_t)ids[t] * D_))[d4];
}

// ---------------- fused residual-add + RMSNorm ----------------
// res = x + (first ? 0 : res);  out = res * rsqrt(mean(res^2)+eps) * w
__global__ __launch_bounds__(256)
void rmsnorm_add(const float* __restrict__ x, float* __restrict__ res,
                 const float* __restrict__ w, float* __restrict__ out,
                 int first) {
  const int row = blockIdx.x;
  const int tid = threadIdx.x;
  const size_t base = (size_t)row * D_;
  float4v v0 = ((const float4v*)(x + base))[tid * 2];
  float4v v1 = ((const float4v*)(x + base))[tid * 2 + 1];
  if (!first) {
    v0 += ((const float4v*)(res + base))[tid * 2];
    v1 += ((const float4v*)(res + base))[tid * 2 + 1];
  }
  ((float4v*)(res + base))[tid * 2]     = v0;
  ((float4v*)(res + base))[tid * 2 + 1] = v1;
  float ss = v0[0]*v0[0] + v0[1]*v0[1] + v0[2]*v0[2] + v0[3]*v0[3]
           + v1[0]*v1[0] + v1[1]*v1[1] + v1[2]*v1[2] + v1[3]*v1[3];
  #pragma unroll
  for (int off = 32; off > 0; off >>= 1) ss += __shfl_xor(ss, off, 64);
  __shared__ float red[4];
  if ((tid & 63) == 0) red[tid >> 6] = ss;
  __syncthreads();
  float tot = red[0] + red[1] + red[2] + red[3];
  float rs = rsqrtf(tot * (1.0f / D_) + EPS_);
  float4v w0 = ((const float4v*)w)[tid * 2];
  float4v w1 = ((const float4v*)w)[tid * 2 + 1];
  ((float4v*)(out + base))[tid * 2]     = v0 * rs * w0;
  ((float4v*)(out + base))[tid * 2 + 1] = v1 * rs * w1;
}

// ---------------- GEMM: C[M][N] f32 = A[M][K] f32 x Bt[N][K] bf16 ----------------
#define BM 128
#define BN 128
#define BKS 32
#define KP 40   // padded LDS K-stride (80B rows: 16B-aligned b128, ~2-way banks)

__global__ __launch_bounds__(256)
void gemm_a32_bT16(const float* __restrict__ A, const short* __restrict__ Bt,
                   float* __restrict__ C, int M, int N, int K) {
  __shared__ short sA[BM * KP];
  __shared__ short sB[BN * KP];
  const int tid  = threadIdx.x;
  const int lane = tid & 63;
  const int wave = tid >> 6;
  const int wm = (wave >> 1) << 6;       // 2x2 waves of 64x64
  const int wn = (wave & 1) << 6;
  const int row0 = blockIdx.y * BM;
  const int col0 = blockIdx.x * BN;
  const int fr = lane & 15;
  const int fk = (lane >> 4) << 3;
  float4v acc[4][4] = {};

  for (int k0 = 0; k0 < K; k0 += BKS) {
    // stage A tile (128x32 f32 -> bf16), 1024 chunks of 4 floats
    #pragma unroll
    for (int i = 0; i < 4; i++) {
      int c = i * 256 + tid;
      int r = c >> 3, kc = c & 7;
      float4v av = *(const float4v*)(A + (size_t)(row0 + r) * K + k0 + (kc << 2));
      short4v sv;
      sv[0] = f2bf(av[0]); sv[1] = f2bf(av[1]);
      sv[2] = f2bf(av[2]); sv[3] = f2bf(av[3]);
      *(short4v*)(&sA[r * KP + (kc << 2)]) = sv;
    }
    // stage B tile (128 rows x 32 k bf16), 512 chunks of 8 bf16
    #pragma unroll
    for (int i = 0; i < 2; i++) {
      int c = i * 256 + tid;
      int r = c >> 2, kc = c & 3;
      short8v bv = *(const short8v*)(Bt + (size_t)(col0 + r) * K + k0 + (kc << 3));
      *(short8v*)(&sB[r * KP + (kc << 3)]) = bv;
    }
    __syncthreads();
    short8v af[4], bf[4];
    #pragma unroll
    for (int f = 0; f < 4; f++) {
      af[f] = *(const short8v*)(&sA[(wm + f * 16 + fr) * KP + fk]);
      bf[f] = *(const short8v*)(&sB[(wn + f * 16 + fr) * KP + fk]);
    }
    #pragma unroll
    for (int i = 0; i < 4; i++)
      #pragma unroll
      for (int j = 0; j < 4; j++)
        acc[i][j] = __builtin_amdgcn_mfma_f32_16x16x32_bf16(af[i], bf[j], acc[i][j], 0, 0, 0);
    __syncthreads();
  }
  const int cr = (lane >> 4) << 2;
  const int cc = lane & 15;
  #pragma unroll
  for (int i = 0; i < 4; i++)
    #pragma unroll
    for (int j = 0; j < 4; j++) {
      size_t base = (size_t)(row0 + wm + i * 16 + cr) * N + col0 + wn + j * 16 + cc;
      #pragma unroll
      for (int r = 0; r < 4; r++)
        C[base + (size_t)r * N] = acc[i][j][r];
    }
}

// ---------------- RoPE (neox rotate-half), in-place on qkv ----------------
__global__ __launch_bounds__(256)
void rope_kernel(const int* __restrict__ positions, float* __restrict__ qkv) {
  int i = blockIdx.x * 256 + threadIdx.x;     // over T * 40 heads * 32 pairs
  int t = i / 1280;
  int r = i - t * 1280;
  int head = r >> 5;
  int ii = r & 31;
  float pos = (float)positions[t];
  float freq = expf(-(float)ii * (9.210340371976184f / 32.0f));  // 10000^(-ii/32)
  float ang = pos * freq;
  float s = sinf(ang), c = cosf(ang);
  float* base = qkv + (size_t)t * 3072 +
                (head < HQ_ ? head * 64 : 2048 + (head - HQ_) * 64);
  float x1 = base[ii], x2 = base[ii + 32];
  base[ii]      = x1 * c - x2 * s;
  base[ii + 32] = x2 * c + x1 * s;
}

// ---------------- causal GQA attention: one wave per (b, h, q-row) ----------------
__global__ __launch_bounds__(256)
void attn_kernel(const float* __restrict__ qkv, float* __restrict__ o) {
  int gw   = (int)(((size_t)blockIdx.x * 256 + threadIdx.x) >> 6);
  int lane = threadIdx.x & 63;
  int m = gw & (S_ - 1);
  int h = (gw >> 10) & (HQ_ - 1);
  int b = gw >> 15;
  int kh = h >> 2;                    // GROUP = 4
  const float* Q  = qkv + (size_t)(b * S_ + m) * 3072 + h * 64;
  const float* Kp = qkv + (size_t)(b * S_) * 3072 + 2048 + kh * 64;
  const float* Vp = Kp + 512;
  float ql = Q[lane] * SCALE_;
  float Mv = -1e30f, Lv = 0.0f, oacc = 0.0f;
  int nb = m >> 6;
  for (int jb = 0; jb <= nb; jb++) {
    int j = (jb << 6) + lane;
    const float* Krow = Kp + (size_t)j * 3072;
    // phase A: score for this lane's key (4 partial sums break the FMA chain)
    float s0 = 0.f, s1 = 0.f, s2 = 0.f, s3 = 0.f;
    #pragma unroll
    for (int d = 0; d < 64; d += 4) {
      s0 += __shfl(ql, d,     64) * Krow[d];
      s1 += __shfl(ql, d + 1, 64) * Krow[d + 1];
      s2 += __shfl(ql, d + 2, 64) * Krow[d + 2];
      s3 += __shfl(ql, d + 3, 64) * Krow[d + 3];
    }
    float s = (s0 + s1) + (s2 + s3);
    if (j > m) s = -1e30f;
    float pm = s;
    #pragma unroll
    for (int off = 32; off > 0; off >>= 1) pm = fmaxf(pm, __shfl_xor(pm, off, 64));
    float newM = fmaxf(Mv, pm);
    float corr = __expf(Mv - newM);
    float p = __expf(s - newM);
    Mv = newM;
    float psum = p;
    #pragma unroll
    for (int off = 32; off > 0; off >>= 1) psum += __shfl_xor(psum, off, 64);
    Lv = Lv * corr + psum;
    // phase B: o_d += sum_j p_j * V[j][d]   (lane = d, coalesced V)
    const float* Vb = Vp + (size_t)(jb << 6) * 3072;
    float b0 = 0.f, b1 = 0.f, b2 = 0.f, b3 = 0.f;
    #pragma unroll
    for (int jj = 0; jj < 64; jj += 4) {
      b0 += __shfl(p, jj,     64) * Vb[(size_t)(jj)     * 3072 + lane];
      b1 += __shfl(p, jj + 1, 64) * Vb[(size_t)(jj + 1) * 3072 + lane];
      b2 += __shfl(p, jj + 2, 64) * Vb[(size_t)(jj + 2) * 3072 + lane];
      b3 += __shfl(p, jj + 3, 64) * Vb[(size_t)(jj + 3) * 3072 + lane];
    }
    oacc = oacc * corr + (b0 + b1) + (b2 + b3);
  }
  o[(size_t)(b * S_ + m) * 2048 + h * 64 + lane] = oacc / Lv;
}

// ---------------- SwiGLU ----------------
__global__ __launch_bounds__(256)
void swiglu_kernel(const float* __restrict__ gu, float* __restrict__ mlp) {
  size_t i = (size_t)blockIdx.x * 256 + threadIdx.x;   // over T*I/4
  size_t t = i / 1408;                                  // I/4 = 1408
  int c = (int)(i - t * 1408);
  float4v g = ((const float4v*)(gu + t * 11264))[c];
  float4v u = ((const float4v*)(gu + t * 11264 + 5632))[c];
  float4v r;
  #pragma unroll
  for (int k = 0; k < 4; k++) r[k] = g[k] / (1.0f + __expf(-g[k])) * u[k];
  ((float4v*)mlp)[i] = r;
}

// ---------------- launch ----------------
extern "C" void kernel_launch(void* const* d_in, const int* in_sizes, int n_in,
                              void* d_out, int out_size, void* d_ws, size_t ws_size,
                              hipStream_t stream) {
  const int*   ids   = (const int*)d_in[0];
  const int*   pos   = (const int*)d_in[1];
  const float* embed = (const float*)d_in[2];
  const float* w_qkv = (const float*)d_in[3];
  const float* w_o   = (const float*)d_in[4];
  const float* w_gu  = (const float*)d_in[5];
  const float* w_dn  = (const float*)d_in[6];
  const float* ln1   = (const float*)d_in[7];
  const float* ln2   = (const float*)d_in[8];
  const float* normw = (const float*)d_in[9];
  float* out = (float*)d_out;

  char* p = (char*)d_ws;
  short* wT  = (short*)p; p += (size_t)11264 * 2048 * 2;        // 46.1 MB (max weight)
  float* h   = (float*)p; p += (size_t)T_ * D_ * 4;
  float* res = (float*)p; p += (size_t)T_ * D_ * 4;
  float* hn  = (float*)p; p += (size_t)T_ * D_ * 4;
  float* big1 = (float*)p; p += (size_t)T_ * 11264 * 4;          // qkv | gate_up
  float* big2 = (float*)p; p += (size_t)T_ * 5632 * 4;           // attn-o | mlp
  float* qkv = big1; float* gu = big1;
  float* ob  = big2; float* mlp = big2;

  dim3 tb(32, 8);
  embed_gather<<<T_ * D_ / 4 / 256, 256, 0, stream>>>(ids, embed, h);

  for (int l = 0; l < L_; l++) {
    rmsnorm_add<<<T_, 256, 0, stream>>>(h, res, ln1 + l * D_, hn, l == 0 ? 1 : 0);

    transpose_bf16<<<dim3(3072 / 32, 2048 / 32), tb, 0, stream>>>(
        w_qkv + (size_t)l * 2048 * 3072, wT, 2048, 3072);
    gemm_a32_bT16<<<dim3(3072 / BN, T_ / BM), 256, 0, stream>>>(
        hn, wT, qkv, T_, 3072, 2048);

    rope_kernel<<<T_ * 1280 / 256, 256, 0, stream>>>(pos, qkv);
    attn_kernel<<<T_ * HQ_ / 4, 256, 0, stream>>>(qkv, ob);

    transpose_bf16<<<dim3(2048 / 32, 2048 / 32), tb, 0, stream>>>(
        w_o + (size_t)l * 2048 * 2048, wT, 2048, 2048);
    gemm_a32_bT16<<<dim3(2048 / BN, T_ / BM), 256, 0, stream>>>(
        ob, wT, h, T_, 2048, 2048);

    rmsnorm_add<<<T_, 256, 0, stream>>>(h, res, ln2 + l * D_, hn, 0);

    transpose_bf16<<<dim3(11264 / 32, 2048 / 32), tb, 0, stream>>>(
        w_gu + (size_t)l * 2048 * 11264, wT, 2048, 11264);
    gemm_a32_bT16<<<dim3(11264 / BN, T_ / BM), 256, 0, stream>>>(
        hn, wT, gu, T_, 11264, 2048);

    swiglu_kernel<<<T_ * 1408 / 256, 256, 0, stream>>>(gu, mlp);

    transpose_bf16<<<dim3(2048 / 32, 5632 / 32), tb, 0, stream>>>(
        w_dn + (size_t)l * 5632 * 2048, wT, 5632, 2048);
    gemm_a32_bT16<<<dim3(2048 / BN, T_ / BM), 256, 0, stream>>>(
        mlp, wT, h, T_, 2048, 5632);
  }
  rmsnorm_add<<<T_, 256, 0, stream>>>(h, res, normw, out, 0);
}

// Round 2
// 2734.314 us; speedup vs baseline: 2.9667x; 2.9667x over previous
//
#include <hip/hip_runtime.h>
#include <hip/hip_bf16.h>

#define B_ 2
#define S_ 1024
#define T_ (B_*S_)
#define D_ 2048
#define L_ 4
#define HQ_ 32
#define HKV_ 8
#define HD_ 64
#define I_ 5632
#define EPS_ 1e-5f
#define SCALE_ 0.125f

typedef __attribute__((ext_vector_type(4))) float  float4v;
typedef __attribute__((ext_vector_type(8))) short  short8v;
typedef __attribute__((ext_vector_type(4))) short  short4v;

__device__ __forceinline__ short f2bf(float f) {
  union { float f; unsigned u; } c; c.f = f;
  unsigned u = c.u + 0x7fffu + ((c.u >> 16) & 1u);
  return (short)(u >> 16);
}

// ---------------- transpose f32 [K][N] -> bf16 [N][K] ----------------
__global__ __launch_bounds__(256)
void transpose_bf16(const float* __restrict__ in, short* __restrict__ out,
                    int K, int N) {
  __shared__ float t[32][33];
  const int bx = blockIdx.x * 32;   // N offset
  const int by = blockIdx.y * 32;   // K offset
  const int tx = threadIdx.x, ty = threadIdx.y;
  #pragma unroll
  for (int j = 0; j < 32; j += 8)
    t[ty + j][tx] = in[(size_t)(by + ty + j) * N + bx + tx];
  __syncthreads();
  #pragma unroll
  for (int j = 0; j < 32; j += 8)
    out[(size_t)(bx + ty + j) * K + by + tx] = f2bf(t[tx][ty + j]);
}

// ---------------- embedding gather ----------------
__global__ __launch_bounds__(256)
void embed_gather(const int* __restrict__ ids, const float* __restrict__ embed,
                  float* __restrict__ h) {
  size_t i = (size_t)blockIdx.x * 256 + threadIdx.x;   // over T*D/4
  int t  = (int)(i >> 9);                              // D/4 = 512
  int d4 = (int)(i & 511);
  ((float4v*)h)[i] = ((const float4v*)(embed + (size_t)ids[t] * D_))[d4];
}

// ---------------- fused residual-add + RMSNorm ----------------
__global__ __launch_bounds__(256)
void rmsnorm_add(const float* __restrict__ x, float* __restrict__ res,
                 const float* __restrict__ w, float* __restrict__ out,
                 int first) {
  const int row = blockIdx.x;
  const int tid = threadIdx.x;
  const size_t base = (size_t)row * D_;
  float4v v0 = ((const float4v*)(x + base))[tid * 2];
  float4v v1 = ((const float4v*)(x + base))[tid * 2 + 1];
  if (!first) {
    v0 += ((const float4v*)(res + base))[tid * 2];
    v1 += ((const float4v*)(res + base))[tid * 2 + 1];
  }
  ((float4v*)(res + base))[tid * 2]     = v0;
  ((float4v*)(res + base))[tid * 2 + 1] = v1;
  float ss = v0[0]*v0[0] + v0[1]*v0[1] + v0[2]*v0[2] + v0[3]*v0[3]
           + v1[0]*v1[0] + v1[1]*v1[1] + v1[2]*v1[2] + v1[3]*v1[3];
  #pragma unroll
  for (int off = 32; off > 0; off >>= 1) ss += __shfl_xor(ss, off, 64);
  __shared__ float red[4];
  if ((tid & 63) == 0) red[tid >> 6] = ss;
  __syncthreads();
  float tot = red[0] + red[1] + red[2] + red[3];
  float rs = rsqrtf(tot * (1.0f / D_) + EPS_);
  float4v w0 = ((const float4v*)w)[tid * 2];
  float4v w1 = ((const float4v*)w)[tid * 2 + 1];
  ((float4v*)(out + base))[tid * 2]     = v0 * rs * w0;
  ((float4v*)(out + base))[tid * 2 + 1] = v1 * rs * w1;
}

// ---------------- GEMM: C[M][N] f32 = A[M][K] f32 x Bt[N][K] bf16 ----------------
#define BM 128
#define BN 128
#define BKS 32
#define KP 40   // padded LDS K-stride

__global__ __launch_bounds__(256)
void gemm_a32_bT16(const float* __restrict__ A, const short* __restrict__ Bt,
                   float* __restrict__ C, int M, int N, int K) {
  __shared__ short sA[BM * KP];
  __shared__ short sB[BN * KP];
  const int tid  = threadIdx.x;
  const int lane = tid & 63;
  const int wave = tid >> 6;
  const int wm = (wave >> 1) << 6;
  const int wn = (wave & 1) << 6;
  const int row0 = blockIdx.y * BM;
  const int col0 = blockIdx.x * BN;
  const int fr = lane & 15;
  const int fk = (lane >> 4) << 3;
  float4v acc[4][4] = {};

  for (int k0 = 0; k0 < K; k0 += BKS) {
    #pragma unroll
    for (int i = 0; i < 4; i++) {
      int c = i * 256 + tid;
      int r = c >> 3, kc = c & 7;
      float4v av = *(const float4v*)(A + (size_t)(row0 + r) * K + k0 + (kc << 2));
      short4v sv;
      sv[0] = f2bf(av[0]); sv[1] = f2bf(av[1]);
      sv[2] = f2bf(av[2]); sv[3] = f2bf(av[3]);
      *(short4v*)(&sA[r * KP + (kc << 2)]) = sv;
    }
    #pragma unroll
    for (int i = 0; i < 2; i++) {
      int c = i * 256 + tid;
      int r = c >> 2, kc = c & 3;
      short8v bv = *(const short8v*)(Bt + (size_t)(col0 + r) * K + k0 + (kc << 3));
      *(short8v*)(&sB[r * KP + (kc << 3)]) = bv;
    }
    __syncthreads();
    short8v af[4], bf[4];
    #pragma unroll
    for (int f = 0; f < 4; f++) {
      af[f] = *(const short8v*)(&sA[(wm + f * 16 + fr) * KP + fk]);
      bf[f] = *(const short8v*)(&sB[(wn + f * 16 + fr) * KP + fk]);
    }
    #pragma unroll
    for (int i = 0; i < 4; i++)
      #pragma unroll
      for (int j = 0; j < 4; j++)
        acc[i][j] = __builtin_amdgcn_mfma_f32_16x16x32_bf16(af[i], bf[j], acc[i][j], 0, 0, 0);
    __syncthreads();
  }
  const int cr = (lane >> 4) << 2;
  const int cc = lane & 15;
  #pragma unroll
  for (int i = 0; i < 4; i++)
    #pragma unroll
    for (int j = 0; j < 4; j++) {
      size_t base = (size_t)(row0 + wm + i * 16 + cr) * N + col0 + wn + j * 16 + cc;
      #pragma unroll
      for (int r = 0; r < 4; r++)
        C[base + (size_t)r * N] = acc[i][j][r];
    }
}

// ---------------- RoPE cos/sin table: [T][32][2] f32 ----------------
__global__ __launch_bounds__(256)
void rope_table(const int* __restrict__ pos, float* __restrict__ tab) {
  int i = blockIdx.x * 256 + threadIdx.x;  // over T*32
  int t = i >> 5, ii = i & 31;
  float p = (float)pos[t];
  float freq = __expf(-(float)ii * (9.210340371976184f / 32.0f));
  float ang = p * freq;
  tab[2 * i]     = cosf(ang);
  tab[2 * i + 1] = sinf(ang);
}

// ---------------- Q: rope + scale + bf16, head-major [b][h][m][d] ----------------
__global__ __launch_bounds__(256)
void convert_q(const float* __restrict__ qkv, const float* __restrict__ tab,
               short* __restrict__ qbf) {
  int i = blockIdx.x * 256 + threadIdx.x;   // [b][h][m][d8]
  int d  = (i & 3) * 8;
  int m  = (i >> 2) & 1023;
  int h  = (i >> 12) & 31;
  int b  = i >> 17;
  const float* src = qkv + ((size_t)(b * S_ + m)) * 3072 + h * 64;
  const float* tb  = tab + ((size_t)(b * S_ + m)) * 64 + d * 2;
  float4v x1a = *(const float4v*)(src + d);
  float4v x1b = *(const float4v*)(src + d + 4);
  float4v x2a = *(const float4v*)(src + d + 32);
  float4v x2b = *(const float4v*)(src + d + 36);
  short8v y1, y2;
  #pragma unroll
  for (int k = 0; k < 4; k++) {
    float c = tb[2 * k], s = tb[2 * k + 1];
    y1[k] = f2bf((x1a[k] * c - x2a[k] * s) * SCALE_);
    y2[k] = f2bf((x2a[k] * c + x1a[k] * s) * SCALE_);
  }
  #pragma unroll
  for (int k = 0; k < 4; k++) {
    float c = tb[2 * (k + 4)], s = tb[2 * (k + 4) + 1];
    y1[k + 4] = f2bf((x1b[k] * c - x2b[k] * s) * SCALE_);
    y2[k + 4] = f2bf((x2b[k] * c + x1b[k] * s) * SCALE_);
  }
  short* dst = qbf + ((size_t)((b * HQ_ + h) * S_ + m)) * HD_ + d;
  *(short8v*)dst = y1;
  *(short8v*)(dst + 32) = y2;
}

// ---------------- K (rope) + V^T, bf16, head-major ----------------
#define KPAD 68

__global__ __launch_bounds__(256)
void convert_kv(const float* __restrict__ qkv, const float* __restrict__ tab,
                short* __restrict__ kbf, short* __restrict__ vtbf) {
  __shared__ short sv[64 * KPAD];
  const int jt = blockIdx.x, kh = blockIdx.y, b = blockIdx.z;
  const int tid = threadIdx.x;
  const int r = tid >> 2;
  const int d = (tid & 3) * 8;
  const int j = jt * 64 + r;
  const float* src = qkv + ((size_t)(b * S_ + j)) * 3072 + 2048 + kh * 64;
  const float* tb  = tab + ((size_t)(b * S_ + j)) * 64 + d * 2;
  float4v x1a = *(const float4v*)(src + d);
  float4v x1b = *(const float4v*)(src + d + 4);
  float4v x2a = *(const float4v*)(src + d + 32);
  float4v x2b = *(const float4v*)(src + d + 36);
  short8v y1, y2;
  #pragma unroll
  for (int k = 0; k < 4; k++) {
    float c = tb[2 * k], s = tb[2 * k + 1];
    y1[k] = f2bf(x1a[k] * c - x2a[k] * s);
    y2[k] = f2bf(x2a[k] * c + x1a[k] * s);
  }
  #pragma unroll
  for (int k = 0; k < 4; k++) {
    float c = tb[2 * (k + 4)], s = tb[2 * (k + 4) + 1];
    y1[k + 4] = f2bf(x1b[k] * c - x2b[k] * s);
    y2[k + 4] = f2bf(x2b[k] * c + x1b[k] * s);
  }
  short* kd = kbf + ((size_t)((b * HKV_ + kh) * S_ + j)) * HD_ + d;
  *(short8v*)kd = y1;
  *(short8v*)(kd + 32) = y2;
  // V (no rope) -> LDS bf16 [j][d]
  const float* vsrc = src + 512;
  float4v va = *(const float4v*)(vsrc + d);
  float4v vb = *(const float4v*)(vsrc + d + 4);
  float4v vc = *(const float4v*)(vsrc + d + 32);
  float4v vd = *(const float4v*)(vsrc + d + 36);
  short8v w1, w2;
  #pragma unroll
  for (int k = 0; k < 4; k++) {
    w1[k] = f2bf(va[k]); w1[k + 4] = f2bf(vb[k]);
    w2[k] = f2bf(vc[k]); w2[k + 4] = f2bf(vd[k]);
  }
  *(short8v*)(&sv[r * KPAD + d])      = w1;
  *(short8v*)(&sv[r * KPAD + d + 32]) = w2;
  __syncthreads();
  // transpose out: vT[b][kh][d][j]
  const int dc = tid >> 2;
  const int jc = (tid & 3) * 16;
  short8v o1, o2;
  #pragma unroll
  for (int k = 0; k < 8; k++) o1[k] = sv[(jc + k) * KPAD + dc];
  #pragma unroll
  for (int k = 0; k < 8; k++) o2[k] = sv[(jc + 8 + k) * KPAD + dc];
  short* od = vtbf + ((size_t)((b * HKV_ + kh) * HD_ + dc)) * S_ + jt * 64 + jc;
  *(short8v*)od       = o1;
  *(short8v*)(od + 8) = o2;
}

// ---------------- MFMA flash attention ----------------
// grid (qb, h, b); 4 waves x 16 q-rows = 64 q rows per block; KV tile = 64
__global__ __launch_bounds__(256)
void attn_mfma(const short* __restrict__ qbf, const short* __restrict__ kbf,
               const short* __restrict__ vtbf, float* __restrict__ o) {
  __shared__ short sK[64 * KPAD];        // [k][d]
  __shared__ short sVt[64 * KPAD];       // [d][k]
  __shared__ short sP[4][16 * KPAD];     // per-wave [q][k]
  const int qb = blockIdx.x;
  const int h  = blockIdx.y;
  const int b  = blockIdx.z;
  const int kh = h >> 2;
  const int tid  = threadIdx.x;
  const int lane = tid & 63;
  const int wv   = tid >> 6;
  const int q0 = qb * 64;
  const int cc = lane & 15;
  const int g  = lane >> 4;

  short8v qf0, qf1;
  {
    const short* qrow = qbf + ((size_t)((b * HQ_ + h) * S_ + q0 + wv * 16 + cc)) * HD_;
    qf0 = *(const short8v*)(qrow + g * 8);
    qf1 = *(const short8v*)(qrow + g * 8 + 32);
  }
  float4v accO[4] = {};
  float m_r[4], l_r[4];
  #pragma unroll
  for (int r = 0; r < 4; r++) { m_r[r] = -1e30f; l_r[r] = 0.f; }

  const short* kb = kbf  + ((size_t)(b * HKV_ + kh)) * S_ * HD_;
  const short* vb = vtbf + ((size_t)(b * HKV_ + kh)) * HD_ * S_;

  for (int jt = 0; jt <= qb; jt++) {
    const int j0 = jt * 64;
    #pragma unroll
    for (int it = 0; it < 2; it++) {
      int idx = it * 256 + tid;
      int rr = idx >> 3, ch = (idx & 7) * 8;
      *(short8v*)(&sK[rr * KPAD + ch])  = *(const short8v*)(kb + (size_t)(j0 + rr) * HD_ + ch);
      *(short8v*)(&sVt[rr * KPAD + ch]) = *(const short8v*)(vb + (size_t)rr * S_ + j0 + ch);
    }
    __syncthreads();

    // QK^T: S tile 16(q) x 64(k)
    float4v sc[4] = {};
    #pragma unroll
    for (int ct = 0; ct < 4; ct++) {
      short8v k0 = *(const short8v*)(&sK[(ct * 16 + cc) * KPAD + g * 8]);
      short8v k1 = *(const short8v*)(&sK[(ct * 16 + cc) * KPAD + g * 8 + 32]);
      sc[ct] = __builtin_amdgcn_mfma_f32_16x16x32_bf16(qf0, k0, sc[ct], 0, 0, 0);
      sc[ct] = __builtin_amdgcn_mfma_f32_16x16x32_bf16(qf1, k1, sc[ct], 0, 0, 0);
    }
    if (jt == qb) {
      #pragma unroll
      for (int ct = 0; ct < 4; ct++)
        #pragma unroll
        for (int r = 0; r < 4; r++)
          if (j0 + ct * 16 + cc > q0 + wv * 16 + g * 4 + r) sc[ct][r] = -1e30f;
    }
    // online softmax (rows live in 16-lane groups)
    float corr[4];
    #pragma unroll
    for (int r = 0; r < 4; r++) {
      float pm = fmaxf(fmaxf(sc[0][r], sc[1][r]), fmaxf(sc[2][r], sc[3][r]));
      pm = fmaxf(pm, __shfl_xor(pm, 1, 64));
      pm = fmaxf(pm, __shfl_xor(pm, 2, 64));
      pm = fmaxf(pm, __shfl_xor(pm, 4, 64));
      pm = fmaxf(pm, __shfl_xor(pm, 8, 64));
      float mn = fmaxf(m_r[r], pm);
      corr[r] = __expf(m_r[r] - mn);
      m_r[r] = mn;
      float rs = 0.f;
      #pragma unroll
      for (int ct = 0; ct < 4; ct++) {
        float p = __expf(sc[ct][r] - mn);
        sc[ct][r] = p;
        rs += p;
      }
      rs += __shfl_xor(rs, 1, 64);
      rs += __shfl_xor(rs, 2, 64);
      rs += __shfl_xor(rs, 4, 64);
      rs += __shfl_xor(rs, 8, 64);
      l_r[r] = l_r[r] * corr[r] + rs;
    }
    // P -> LDS (bf16), rescale O
    #pragma unroll
    for (int ct = 0; ct < 4; ct++)
      #pragma unroll
      for (int r = 0; r < 4; r++)
        sP[wv][(g * 4 + r) * KPAD + ct * 16 + cc] = f2bf(sc[ct][r]);
    #pragma unroll
    for (int dt = 0; dt < 4; dt++)
      #pragma unroll
      for (int r = 0; r < 4; r++)
        accO[dt][r] *= corr[r];
    short8v pf0 = *(const short8v*)(&sP[wv][cc * KPAD + g * 8]);
    short8v pf1 = *(const short8v*)(&sP[wv][cc * KPAD + g * 8 + 32]);
    #pragma unroll
    for (int dt = 0; dt < 4; dt++) {
      short8v v0 = *(const short8v*)(&sVt[(dt * 16 + cc) * KPAD + g * 8]);
      short8v v1 = *(const short8v*)(&sVt[(dt * 16 + cc) * KPAD + g * 8 + 32]);
      accO[dt] = __builtin_amdgcn_mfma_f32_16x16x32_bf16(pf0, v0, accO[dt], 0, 0, 0);
      accO[dt] = __builtin_amdgcn_mfma_f32_16x16x32_bf16(pf1, v1, accO[dt], 0, 0, 0);
    }
    __syncthreads();
  }
  #pragma unroll
  for (int dt = 0; dt < 4; dt++)
    #pragma unroll
    for (int r = 0; r < 4; r++) {
      int q = q0 + wv * 16 + g * 4 + r;
      o[((size_t)(b * S_ + q)) * 2048 + h * 64 + dt * 16 + cc] = accO[dt][r] / l_r[r];
    }
}

// ---------------- SwiGLU ----------------
__global__ __launch_bounds__(256)
void swiglu_kernel(const float* __restrict__ gu, float* __restrict__ mlp) {
  size_t i = (size_t)blockIdx.x * 256 + threadIdx.x;
  size_t t = i / 1408;
  int c = (int)(i - t * 1408);
  float4v g = ((const float4v*)(gu + t * 11264))[c];
  float4v u = ((const float4v*)(gu + t * 11264 + 5632))[c];
  float4v r;
  #pragma unroll
  for (int k = 0; k < 4; k++) r[k] = g[k] / (1.0f + __expf(-g[k])) * u[k];
  ((float4v*)mlp)[i] = r;
}

// ---------------- launch ----------------
extern "C" void kernel_launch(void* const* d_in, const int* in_sizes, int n_in,
                              void* d_out, int out_size, void* d_ws, size_t ws_size,
                              hipStream_t stream) {
  const int*   ids   = (const int*)d_in[0];
  const int*   pos   = (const int*)d_in[1];
  const float* embed = (const float*)d_in[2];
  const float* w_qkv = (const float*)d_in[3];
  const float* w_o   = (const float*)d_in[4];
  const float* w_gu  = (const float*)d_in[5];
  const float* w_dn  = (const float*)d_in[6];
  const float* ln1   = (const float*)d_in[7];
  const float* ln2   = (const float*)d_in[8];
  const float* normw = (const float*)d_in[9];
  float* out = (float*)d_out;

  char* p = (char*)d_ws;
  short* wT  = (short*)p; p += (size_t)11264 * 2048 * 2;
  float* h   = (float*)p; p += (size_t)T_ * D_ * 4;
  float* res = (float*)p; p += (size_t)T_ * D_ * 4;
  float* hn  = (float*)p; p += (size_t)T_ * D_ * 4;
  float* big1 = (float*)p; p += (size_t)T_ * 11264 * 4;
  float* big2 = (float*)p; p += (size_t)T_ * 5632 * 4;
  float* tab = (float*)p; p += (size_t)T_ * 64 * 4;
  short* qbf = (short*)p; p += (size_t)B_ * HQ_ * S_ * HD_ * 2;
  short* kbf = (short*)p; p += (size_t)B_ * HKV_ * S_ * HD_ * 2;
  short* vtbf = (short*)p; p += (size_t)B_ * HKV_ * HD_ * S_ * 2;
  float* qkv = big1; float* gu = big1;
  float* ob  = big2; float* mlp = big2;

  dim3 tb(32, 8);
  embed_gather<<<T_ * D_ / 4 / 256, 256, 0, stream>>>(ids, embed, h);
  rope_table<<<T_ * 32 / 256, 256, 0, stream>>>(pos, tab);

  for (int l = 0; l < L_; l++) {
    rmsnorm_add<<<T_, 256, 0, stream>>>(h, res, ln1 + l * D_, hn, l == 0 ? 1 : 0);

    transpose_bf16<<<dim3(3072 / 32, 2048 / 32), tb, 0, stream>>>(
        w_qkv + (size_t)l * 2048 * 3072, wT, 2048, 3072);
    gemm_a32_bT16<<<dim3(3072 / BN, T_ / BM), 256, 0, stream>>>(
        hn, wT, qkv, T_, 3072, 2048);

    convert_q<<<1024, 256, 0, stream>>>(qkv, tab, qbf);
    convert_kv<<<dim3(16, 8, 2), 256, 0, stream>>>(qkv, tab, kbf, vtbf);
    attn_mfma<<<dim3(16, 32, 2), 256, 0, stream>>>(qbf, kbf, vtbf, ob);

    transpose_bf16<<<dim3(2048 / 32, 2048 / 32), tb, 0, stream>>>(
        w_o + (size_t)l * 2048 * 2048, wT, 2048, 2048);
    gemm_a32_bT16<<<dim3(2048 / BN, T_ / BM), 256, 0, stream>>>(
        ob, wT, h, T_, 2048, 2048);

    rmsnorm_add<<<T_, 256, 0, stream>>>(h, res, ln2 + l * D_, hn, 0);

    transpose_bf16<<<dim3(11264 / 32, 2048 / 32), tb, 0, stream>>>(
        w_gu + (size_t)l * 2048 * 11264, wT, 2048, 11264);
    gemm_a32_bT16<<<dim3(11264 / BN, T_ / BM), 256, 0, stream>>>(
        hn, wT, gu, T_, 11264, 2048);

    swiglu_kernel<<<T_ * 1408 / 256, 256, 0, stream>>>(gu, mlp);

    transpose_bf16<<<dim3(2048 / 32, 5632 / 32), tb, 0, stream>>>(
        w_dn + (size_t)l * 5632 * 2048, wT, 5632, 2048);
    gemm_a32_bT16<<<dim3(2048 / BN, T_ / BM), 256, 0, stream>>>(
        mlp, wT, h, T_, 2048, 5632);
  }
  rmsnorm_add<<<T_, 256, 0, stream>>>(h, res, normw, out, 0);
}

// Round 3
// 2188.014 us; speedup vs baseline: 3.7074x; 1.2497x over previous
//
#include <hip/hip_runtime.h>
#include <hip/hip_bf16.h>

#define B_ 2
#define S_ 1024
#define T_ (B_*S_)
#define D_ 2048
#define L_ 4
#define HQ_ 32
#define HKV_ 8
#define HD_ 64
#define I_ 5632
#define EPS_ 1e-5f
#define SCALE_ 0.125f

typedef __attribute__((ext_vector_type(4))) float  float4v;
typedef __attribute__((ext_vector_type(8))) short  short8v;
typedef __attribute__((ext_vector_type(4))) short  short4v;

#define GLOAD16(g, l) \
  __builtin_amdgcn_global_load_lds((const __attribute__((address_space(1))) void*)(g), \
                                   (__attribute__((address_space(3))) void*)(l), 16, 0, 0)

__device__ __forceinline__ short f2bf(float f) {
  union { float f; unsigned u; } c; c.f = f;
  unsigned u = c.u + 0x7fffu + ((c.u >> 16) & 1u);
  return (short)(u >> 16);
}

// ---------------- transpose f32 [K][N] -> bf16 [N][K] ----------------
__global__ __launch_bounds__(256)
void transpose_bf16(const float* __restrict__ in, short* __restrict__ out,
                    int K, int N) {
  __shared__ float t[32][33];
  const int bx = blockIdx.x * 32;
  const int by = blockIdx.y * 32;
  const int tx = threadIdx.x, ty = threadIdx.y;
  #pragma unroll
  for (int j = 0; j < 32; j += 8)
    t[ty + j][tx] = in[(size_t)(by + ty + j) * N + bx + tx];
  __syncthreads();
  #pragma unroll
  for (int j = 0; j < 32; j += 8)
    out[(size_t)(bx + ty + j) * K + by + tx] = f2bf(t[tx][ty + j]);
}

// ---------------- embedding gather ----------------
__global__ __launch_bounds__(256)
void embed_gather(const int* __restrict__ ids, const float* __restrict__ embed,
                  float* __restrict__ h) {
  size_t i = (size_t)blockIdx.x * 256 + threadIdx.x;
  int t  = (int)(i >> 9);
  int d4 = (int)(i & 511);
  ((float4v*)h)[i] = ((const float4v*)(embed + (size_t)ids[t] * D_))[d4];
}

// ---------------- fused residual-add + RMSNorm (bf16 or f32 out) ----------------
__global__ __launch_bounds__(256)
void rmsnorm_add(const float* __restrict__ x, float* __restrict__ res,
                 const float* __restrict__ w, void* __restrict__ outp,
                 int first, int bf16out) {
  const int row = blockIdx.x;
  const int tid = threadIdx.x;
  const size_t base = (size_t)row * D_;
  float4v v0 = ((const float4v*)(x + base))[tid * 2];
  float4v v1 = ((const float4v*)(x + base))[tid * 2 + 1];
  if (!first) {
    v0 += ((const float4v*)(res + base))[tid * 2];
    v1 += ((const float4v*)(res + base))[tid * 2 + 1];
  }
  ((float4v*)(res + base))[tid * 2]     = v0;
  ((float4v*)(res + base))[tid * 2 + 1] = v1;
  float ss = v0[0]*v0[0] + v0[1]*v0[1] + v0[2]*v0[2] + v0[3]*v0[3]
           + v1[0]*v1[0] + v1[1]*v1[1] + v1[2]*v1[2] + v1[3]*v1[3];
  #pragma unroll
  for (int off = 32; off > 0; off >>= 1) ss += __shfl_xor(ss, off, 64);
  __shared__ float red[4];
  if ((tid & 63) == 0) red[tid >> 6] = ss;
  __syncthreads();
  float tot = red[0] + red[1] + red[2] + red[3];
  float rs = rsqrtf(tot * (1.0f / D_) + EPS_);
  float4v w0 = ((const float4v*)w)[tid * 2];
  float4v w1 = ((const float4v*)w)[tid * 2 + 1];
  float4v o0 = v0 * rs * w0;
  float4v o1 = v1 * rs * w1;
  if (bf16out) {
    short8v y;
    #pragma unroll
    for (int k = 0; k < 4; k++) { y[k] = f2bf(o0[k]); y[k + 4] = f2bf(o1[k]); }
    ((short8v*)((char*)outp + base * 2))[tid] = y;
  } else {
    float* op = (float*)outp + base;
    ((float4v*)op)[tid * 2]     = o0;
    ((float4v*)op)[tid * 2 + 1] = o1;
  }
}

// ------- GEMM (m97 structure): C[M][N] f32 = A[M][K] bf16 x Bt[N][K] bf16 -------
#define BM 128
#define BN 128
#define BKS 32

__global__ __launch_bounds__(256)
void gemm_bf16(const short* __restrict__ A, const short* __restrict__ Bt,
               float* __restrict__ C, int M, int N, int K) {
  __shared__ short sA[BM * BKS];   // linear, no padding (global_load_lds dest)
  __shared__ short sB[BN * BKS];
  const int tid  = threadIdx.x;
  const int lane = tid & 63;
  const int wave = tid >> 6;
  const int wm = (wave >> 1) << 6;
  const int wn = (wave & 1) << 6;
  const int row0 = blockIdx.y * BM;
  const int col0 = blockIdx.x * BN;
  const int fr = lane & 15;
  const int fk = (lane >> 4) << 3;
  float4v acc[4][4] = {};

  // staging: chunk c = it*256+tid; row = c>>2, koff = (c&3)*8, LDS off = c*8
  const int r_st  = tid >> 2;
  const int kc_st = (tid & 3) << 3;
  const short* pA = A  + (size_t)(row0 + r_st) * K + kc_st;
  const short* pB = Bt + (size_t)(col0 + r_st) * K + kc_st;
  const size_t stride64 = (size_t)64 * K;
  short* lA0 = &sA[tid * 8];
  short* lA1 = &sA[(256 + tid) * 8];
  short* lB0 = &sB[tid * 8];
  short* lB1 = &sB[(256 + tid) * 8];

  for (int k0 = 0; k0 < K; k0 += BKS) {
    GLOAD16(pA, lA0);
    GLOAD16(pA + stride64, lA1);
    GLOAD16(pB, lB0);
    GLOAD16(pB + stride64, lB1);
    pA += BKS; pB += BKS;
    __syncthreads();            // drains vmcnt -> tiles resident
    short8v af[4], bfr[4];
    #pragma unroll
    for (int f = 0; f < 4; f++) {
      af[f]  = *(const short8v*)(&sA[(wm + f * 16 + fr) * BKS + fk]);
      bfr[f] = *(const short8v*)(&sB[(wn + f * 16 + fr) * BKS + fk]);
    }
    #pragma unroll
    for (int i = 0; i < 4; i++)
      #pragma unroll
      for (int j = 0; j < 4; j++)
        acc[i][j] = __builtin_amdgcn_mfma_f32_16x16x32_bf16(af[i], bfr[j], acc[i][j], 0, 0, 0);
    __syncthreads();            // all waves done reading before next stage
  }
  const int cr = (lane >> 4) << 2;
  const int cc = lane & 15;
  #pragma unroll
  for (int i = 0; i < 4; i++)
    #pragma unroll
    for (int j = 0; j < 4; j++) {
      size_t base = (size_t)(row0 + wm + i * 16 + cr) * N + col0 + wn + j * 16 + cc;
      #pragma unroll
      for (int r = 0; r < 4; r++)
        C[base + (size_t)r * N] = acc[i][j][r];
    }
}

// ---------------- RoPE cos/sin table: [T][32][2] f32 ----------------
__global__ __launch_bounds__(256)
void rope_table(const int* __restrict__ pos, float* __restrict__ tab) {
  int i = blockIdx.x * 256 + threadIdx.x;
  int t = i >> 5, ii = i & 31;
  float p = (float)pos[t];
  float freq = __expf(-(float)ii * (9.210340371976184f / 32.0f));
  float ang = p * freq;
  tab[2 * i]     = cosf(ang);
  tab[2 * i + 1] = sinf(ang);
}

// ---------------- Q: rope + scale + bf16, head-major [b][h][m][d] ----------------
__global__ __launch_bounds__(256)
void convert_q(const float* __restrict__ qkv, const float* __restrict__ tab,
               short* __restrict__ qbf) {
  int i = blockIdx.x * 256 + threadIdx.x;
  int d  = (i & 3) * 8;
  int m  = (i >> 2) & 1023;
  int h  = (i >> 12) & 31;
  int b  = i >> 17;
  const float* src = qkv + ((size_t)(b * S_ + m)) * 3072 + h * 64;
  const float* tb  = tab + ((size_t)(b * S_ + m)) * 64 + d * 2;
  float4v x1a = *(const float4v*)(src + d);
  float4v x1b = *(const float4v*)(src + d + 4);
  float4v x2a = *(const float4v*)(src + d + 32);
  float4v x2b = *(const float4v*)(src + d + 36);
  short8v y1, y2;
  #pragma unroll
  for (int k = 0; k < 4; k++) {
    float c = tb[2 * k], s = tb[2 * k + 1];
    y1[k] = f2bf((x1a[k] * c - x2a[k] * s) * SCALE_);
    y2[k] = f2bf((x2a[k] * c + x1a[k] * s) * SCALE_);
  }
  #pragma unroll
  for (int k = 0; k < 4; k++) {
    float c = tb[2 * (k + 4)], s = tb[2 * (k + 4) + 1];
    y1[k + 4] = f2bf((x1b[k] * c - x2b[k] * s) * SCALE_);
    y2[k + 4] = f2bf((x2b[k] * c + x1b[k] * s) * SCALE_);
  }
  short* dst = qbf + ((size_t)((b * HQ_ + h) * S_ + m)) * HD_ + d;
  *(short8v*)dst = y1;
  *(short8v*)(dst + 32) = y2;
}

// ---------------- K (rope) + V^T, bf16, head-major ----------------
#define KPAD 68

__global__ __launch_bounds__(256)
void convert_kv(const float* __restrict__ qkv, const float* __restrict__ tab,
                short* __restrict__ kbf, short* __restrict__ vtbf) {
  __shared__ short sv[64 * KPAD];
  const int jt = blockIdx.x, kh = blockIdx.y, b = blockIdx.z;
  const int tid = threadIdx.x;
  const int r = tid >> 2;
  const int d = (tid & 3) * 8;
  const int j = jt * 64 + r;
  const float* src = qkv + ((size_t)(b * S_ + j)) * 3072 + 2048 + kh * 64;
  const float* tb  = tab + ((size_t)(b * S_ + j)) * 64 + d * 2;
  float4v x1a = *(const float4v*)(src + d);
  float4v x1b = *(const float4v*)(src + d + 4);
  float4v x2a = *(const float4v*)(src + d + 32);
  float4v x2b = *(const float4v*)(src + d + 36);
  short8v y1, y2;
  #pragma unroll
  for (int k = 0; k < 4; k++) {
    float c = tb[2 * k], s = tb[2 * k + 1];
    y1[k] = f2bf(x1a[k] * c - x2a[k] * s);
    y2[k] = f2bf(x2a[k] * c + x1a[k] * s);
  }
  #pragma unroll
  for (int k = 0; k < 4; k++) {
    float c = tb[2 * (k + 4)], s = tb[2 * (k + 4) + 1];
    y1[k + 4] = f2bf(x1b[k] * c - x2b[k] * s);
    y2[k + 4] = f2bf(x2b[k] * c + x1b[k] * s);
  }
  short* kd = kbf + ((size_t)((b * HKV_ + kh) * S_ + j)) * HD_ + d;
  *(short8v*)kd = y1;
  *(short8v*)(kd + 32) = y2;
  const float* vsrc = src + 512;
  float4v va = *(const float4v*)(vsrc + d);
  float4v vb = *(const float4v*)(vsrc + d + 4);
  float4v vc = *(const float4v*)(vsrc + d + 32);
  float4v vd = *(const float4v*)(vsrc + d + 36);
  short8v w1, w2;
  #pragma unroll
  for (int k = 0; k < 4; k++) {
    w1[k] = f2bf(va[k]); w1[k + 4] = f2bf(vb[k]);
    w2[k] = f2bf(vc[k]); w2[k + 4] = f2bf(vd[k]);
  }
  *(short8v*)(&sv[r * KPAD + d])      = w1;
  *(short8v*)(&sv[r * KPAD + d + 32]) = w2;
  __syncthreads();
  const int dc = tid >> 2;
  const int jc = (tid & 3) * 16;
  short8v o1, o2;
  #pragma unroll
  for (int k = 0; k < 8; k++) o1[k] = sv[(jc + k) * KPAD + dc];
  #pragma unroll
  for (int k = 0; k < 8; k++) o2[k] = sv[(jc + 8 + k) * KPAD + dc];
  short* od = vtbf + ((size_t)((b * HKV_ + kh) * HD_ + dc)) * S_ + jt * 64 + jc;
  *(short8v*)od       = o1;
  *(short8v*)(od + 8) = o2;
}

// ---------------- MFMA flash attention (bf16 out) ----------------
__global__ __launch_bounds__(256)
void attn_mfma(const short* __restrict__ qbf, const short* __restrict__ kbf,
               const short* __restrict__ vtbf, short* __restrict__ obf) {
  __shared__ short sK[64 * KPAD];
  __shared__ short sVt[64 * KPAD];
  __shared__ short sP[4][16 * KPAD];
  const int qb = blockIdx.x;
  const int h  = blockIdx.y;
  const int b  = blockIdx.z;
  const int kh = h >> 2;
  const int tid  = threadIdx.x;
  const int lane = tid & 63;
  const int wv   = tid >> 6;
  const int q0 = qb * 64;
  const int cc = lane & 15;
  const int g  = lane >> 4;

  short8v qf0, qf1;
  {
    const short* qrow = qbf + ((size_t)((b * HQ_ + h) * S_ + q0 + wv * 16 + cc)) * HD_;
    qf0 = *(const short8v*)(qrow + g * 8);
    qf1 = *(const short8v*)(qrow + g * 8 + 32);
  }
  float4v accO[4] = {};
  float m_r[4], l_r[4];
  #pragma unroll
  for (int r = 0; r < 4; r++) { m_r[r] = -1e30f; l_r[r] = 0.f; }

  const short* kb = kbf  + ((size_t)(b * HKV_ + kh)) * S_ * HD_;
  const short* vb = vtbf + ((size_t)(b * HKV_ + kh)) * HD_ * S_;

  for (int jt = 0; jt <= qb; jt++) {
    const int j0 = jt * 64;
    #pragma unroll
    for (int it = 0; it < 2; it++) {
      int idx = it * 256 + tid;
      int rr = idx >> 3, ch = (idx & 7) * 8;
      *(short8v*)(&sK[rr * KPAD + ch])  = *(const short8v*)(kb + (size_t)(j0 + rr) * HD_ + ch);
      *(short8v*)(&sVt[rr * KPAD + ch]) = *(const short8v*)(vb + (size_t)rr * S_ + j0 + ch);
    }
    __syncthreads();

    float4v sc[4] = {};
    #pragma unroll
    for (int ct = 0; ct < 4; ct++) {
      short8v k0 = *(const short8v*)(&sK[(ct * 16 + cc) * KPAD + g * 8]);
      short8v k1 = *(const short8v*)(&sK[(ct * 16 + cc) * KPAD + g * 8 + 32]);
      sc[ct] = __builtin_amdgcn_mfma_f32_16x16x32_bf16(qf0, k0, sc[ct], 0, 0, 0);
      sc[ct] = __builtin_amdgcn_mfma_f32_16x16x32_bf16(qf1, k1, sc[ct], 0, 0, 0);
    }
    if (jt == qb) {
      #pragma unroll
      for (int ct = 0; ct < 4; ct++)
        #pragma unroll
        for (int r = 0; r < 4; r++)
          if (j0 + ct * 16 + cc > q0 + wv * 16 + g * 4 + r) sc[ct][r] = -1e30f;
    }
    float corr[4];
    #pragma unroll
    for (int r = 0; r < 4; r++) {
      float pm = fmaxf(fmaxf(sc[0][r], sc[1][r]), fmaxf(sc[2][r], sc[3][r]));
      pm = fmaxf(pm, __shfl_xor(pm, 1, 64));
      pm = fmaxf(pm, __shfl_xor(pm, 2, 64));
      pm = fmaxf(pm, __shfl_xor(pm, 4, 64));
      pm = fmaxf(pm, __shfl_xor(pm, 8, 64));
      float mn = fmaxf(m_r[r], pm);
      corr[r] = __expf(m_r[r] - mn);
      m_r[r] = mn;
      float rs = 0.f;
      #pragma unroll
      for (int ct = 0; ct < 4; ct++) {
        float p = __expf(sc[ct][r] - mn);
        sc[ct][r] = p;
        rs += p;
      }
      rs += __shfl_xor(rs, 1, 64);
      rs += __shfl_xor(rs, 2, 64);
      rs += __shfl_xor(rs, 4, 64);
      rs += __shfl_xor(rs, 8, 64);
      l_r[r] = l_r[r] * corr[r] + rs;
    }
    #pragma unroll
    for (int ct = 0; ct < 4; ct++)
      #pragma unroll
      for (int r = 0; r < 4; r++)
        sP[wv][(g * 4 + r) * KPAD + ct * 16 + cc] = f2bf(sc[ct][r]);
    #pragma unroll
    for (int dt = 0; dt < 4; dt++)
      #pragma unroll
      for (int r = 0; r < 4; r++)
        accO[dt][r] *= corr[r];
    short8v pf0 = *(const short8v*)(&sP[wv][cc * KPAD + g * 8]);
    short8v pf1 = *(const short8v*)(&sP[wv][cc * KPAD + g * 8 + 32]);
    #pragma unroll
    for (int dt = 0; dt < 4; dt++) {
      short8v v0 = *(const short8v*)(&sVt[(dt * 16 + cc) * KPAD + g * 8]);
      short8v v1 = *(const short8v*)(&sVt[(dt * 16 + cc) * KPAD + g * 8 + 32]);
      accO[dt] = __builtin_amdgcn_mfma_f32_16x16x32_bf16(pf0, v0, accO[dt], 0, 0, 0);
      accO[dt] = __builtin_amdgcn_mfma_f32_16x16x32_bf16(pf1, v1, accO[dt], 0, 0, 0);
    }
    __syncthreads();
  }
  #pragma unroll
  for (int dt = 0; dt < 4; dt++)
    #pragma unroll
    for (int r = 0; r < 4; r++) {
      int q = q0 + wv * 16 + g * 4 + r;
      obf[((size_t)(b * S_ + q)) * 2048 + h * 64 + dt * 16 + cc] = f2bf(accO[dt][r] / l_r[r]);
    }
}

// ---------------- SwiGLU (f32 in, bf16 out) ----------------
__global__ __launch_bounds__(256)
void swiglu_kernel(const float* __restrict__ gu, short* __restrict__ mlp) {
  size_t i = (size_t)blockIdx.x * 256 + threadIdx.x;   // over T*I/8
  size_t t = i / 704;
  int c = (int)(i - t * 704);
  const float* gp = gu + t * 11264 + c * 8;
  const float* up = gp + 5632;
  float4v g0 = *(const float4v*)gp, g1 = *(const float4v*)(gp + 4);
  float4v u0 = *(const float4v*)up, u1 = *(const float4v*)(up + 4);
  short8v r;
  #pragma unroll
  for (int k = 0; k < 4; k++) {
    r[k]     = f2bf(g0[k] / (1.0f + __expf(-g0[k])) * u0[k]);
    r[k + 4] = f2bf(g1[k] / (1.0f + __expf(-g1[k])) * u1[k]);
  }
  ((short8v*)mlp)[i] = r;
}

// ---------------- launch ----------------
extern "C" void kernel_launch(void* const* d_in, const int* in_sizes, int n_in,
                              void* d_out, int out_size, void* d_ws, size_t ws_size,
                              hipStream_t stream) {
  const int*   ids   = (const int*)d_in[0];
  const int*   pos   = (const int*)d_in[1];
  const float* embed = (const float*)d_in[2];
  const float* w_qkv = (const float*)d_in[3];
  const float* w_o   = (const float*)d_in[4];
  const float* w_gu  = (const float*)d_in[5];
  const float* w_dn  = (const float*)d_in[6];
  const float* ln1   = (const float*)d_in[7];
  const float* ln2   = (const float*)d_in[8];
  const float* normw = (const float*)d_in[9];
  float* out = (float*)d_out;

  char* p = (char*)d_ws;
  short* wT    = (short*)p; p += (size_t)11264 * 2048 * 2;
  float* h     = (float*)p; p += (size_t)T_ * D_ * 4;
  float* res   = (float*)p; p += (size_t)T_ * D_ * 4;
  short* hnbf  = (short*)p; p += (size_t)T_ * D_ * 2;
  float* big1  = (float*)p; p += (size_t)T_ * 11264 * 4;   // qkv | gate_up (f32 C)
  short* obf   = (short*)p; p += (size_t)T_ * D_ * 2;      // attn out bf16
  short* mlpbf = (short*)p; p += (size_t)T_ * I_ * 2;      // swiglu out bf16
  float* tab   = (float*)p; p += (size_t)T_ * 64 * 4;
  short* qbf   = (short*)p; p += (size_t)B_ * HQ_ * S_ * HD_ * 2;
  short* kbf   = (short*)p; p += (size_t)B_ * HKV_ * S_ * HD_ * 2;
  short* vtbf  = (short*)p; p += (size_t)B_ * HKV_ * HD_ * S_ * 2;
  float* qkv = big1; float* gu = big1;

  dim3 tb(32, 8);
  embed_gather<<<T_ * D_ / 4 / 256, 256, 0, stream>>>(ids, embed, h);
  rope_table<<<T_ * 32 / 256, 256, 0, stream>>>(pos, tab);

  for (int l = 0; l < L_; l++) {
    rmsnorm_add<<<T_, 256, 0, stream>>>(h, res, ln1 + l * D_, hnbf, l == 0 ? 1 : 0, 1);

    transpose_bf16<<<dim3(3072 / 32, 2048 / 32), tb, 0, stream>>>(
        w_qkv + (size_t)l * 2048 * 3072, wT, 2048, 3072);
    gemm_bf16<<<dim3(3072 / BN, T_ / BM), 256, 0, stream>>>(
        hnbf, wT, qkv, T_, 3072, 2048);

    convert_q<<<1024, 256, 0, stream>>>(qkv, tab, qbf);
    convert_kv<<<dim3(16, 8, 2), 256, 0, stream>>>(qkv, tab, kbf, vtbf);
    attn_mfma<<<dim3(16, 32, 2), 256, 0, stream>>>(qbf, kbf, vtbf, obf);

    transpose_bf16<<<dim3(2048 / 32, 2048 / 32), tb, 0, stream>>>(
        w_o + (size_t)l * 2048 * 2048, wT, 2048, 2048);
    gemm_bf16<<<dim3(2048 / BN, T_ / BM), 256, 0, stream>>>(
        obf, wT, h, T_, 2048, 2048);

    rmsnorm_add<<<T_, 256, 0, stream>>>(h, res, ln2 + l * D_, hnbf, 0, 1);

    transpose_bf16<<<dim3(11264 / 32, 2048 / 32), tb, 0, stream>>>(
        w_gu + (size_t)l * 2048 * 11264, wT, 2048, 11264);
    gemm_bf16<<<dim3(11264 / BN, T_ / BM), 256, 0, stream>>>(
        hnbf, wT, gu, T_, 11264, 2048);

    swiglu_kernel<<<T_ * I_ / 8 / 256, 256, 0, stream>>>(gu, mlpbf);

    transpose_bf16<<<dim3(2048 / 32, 5632 / 32), tb, 0, stream>>>(
        w_dn + (size_t)l * 5632 * 2048, wT, 5632, 2048);
    gemm_bf16<<<dim3(2048 / BN, T_ / BM), 256, 0, stream>>>(
        mlpbf, wT, h, T_, 2048, 5632);
  }
  rmsnorm_add<<<T_, 256, 0, stream>>>(h, res, normw, out, 0, 0);
}